// Round 5
// baseline (1602.192 us; speedup 1.0000x reference)
//
#include <hip/hip_runtime.h>
#include <hip/hip_cooperative_groups.h>

namespace cg = cooperative_groups;

// ---------------------------------------------------------------------------
// GenomeDecoder, R7: ONE cooperative kernel (128 blocks x 512 threads,
// co-resident).  R4 showed non-chain cost ~420-446us is launch-count
// INVARIANT (17 vs 8 launches) -> boundary/drain overhead, not kernel time.
// Fix: zero boundaries.  Every stage keeps R4's wide work decomposition
// (R3 lesson: never serialize; R4 lesson: fewer launches alone don't help):
//   E    embed               128 blk x 2 tokens
//   A(l) qkv+attn            blocks 0-63 (b,head)   } concurrent, l=0
//   P    prepm int8 M        blocks 64-127, 16 rows }
//   F(l) ao+LN1+ffn+LN2      128 blk x 2 tokens
//   LG   latent+gi0          blocks 0-15
//   CH   GRU chain (int8 MFMA recurrence, unchanged R4 code) blocks 0-15
//   EPI  out GEMM            128 blk x 8-9 chunks
// grid.sync() between dependent stages (7 total).  Chain math unchanged:
// mfma_i32_16x16x64_i8, h broadcast rows, parity-split gates, exact int32.
// ---------------------------------------------------------------------------

typedef unsigned int uint_t;
typedef int v4i __attribute__((ext_vector_type(4)));

// ---- workspace layout (4-byte slot indices) ----
static constexpr size_t WS_HB   = 0;        // 16*16*256
static constexpr size_t WS_AO   = 262144;   // 16*16*256
static constexpr size_t WS_GI0  = 593920;   // 16*768
static constexpr size_t WS_CV   = 606208;   // 1024 fused-bias consts
static constexpr size_t WS_MS   = 607232;   // 1024 per-row scales
static constexpr size_t WS_M8   = 608256;   // 1024*64 dwords packed int8 M
static constexpr size_t WS_HSEQ = 673792;   // 1028*16*256 floats

__device__ inline float sigf(float x){
    return __builtin_amdgcn_rcpf(1.0f + __builtin_amdgcn_exp2f(-1.442695041f*x));
}
__device__ inline float tanh_fast(float x){
    return 1.0f - 2.0f*__builtin_amdgcn_rcpf(1.0f + __builtin_amdgcn_exp2f(2.885390082f*x));
}

__global__ __launch_bounds__(512,2) void k_all(
    const float* gs, const float* eW, const float* eb,
    const float* qkvW, const float* qkvb,
    const float* aoW, const float* aob,
    const float* g1, const float* b1, const float* g2, const float* b2v,
    const float* W1, const float* fb1, const float* W2, const float* fb2,
    const float* Wih, const float* bih, const float* Whh, const float* bhh,
    const float* outW, const float* outb,
    float* ws, float* out)
{
    __shared__ float s_h[16][256];            // 16 KB staging (front + epi)
    __shared__ float s_qkv[3][16][64];        // 12 KB q/k/v
    __shared__ float s_sc[16][16];            // 1 KB scores / lat / prepm q8
    __shared__ float s_f1[2][1024];           // 8 KB F1 rows / prepm wrow
    __shared__ float s_red[2][256];           // 2 KB LN partials / prepm red
    __shared__ signed char s_h8[2][256];      // chain h double-buffer

    cg::grid_group grid = cg::this_grid();
    int tid = threadIdx.x;
    int bx  = blockIdx.x;

    // ================= E: embed (2 tokens/block) =================
    {
        int bs = bx*2 + (tid>>8);
        int i  = tid & 255;
        const float* g = gs + bs*16;
        float acc = eb[i];
#pragma unroll
        for(int d=0; d<16; ++d) acc += g[d]*eW[i*16+d];
        ws[WS_HB + (size_t)bs*256 + i] = acc;
    }
    grid.sync();                                            // 1

    for(int l=0; l<2; ++l){
        if(bx < 64){
            // ============ A: qkv + attention, (b,head) ============
            int b = bx>>2, hh = bx&3;
            for(int u=tid; u<4096; u+=512)
                s_h[u>>8][u&255] = ws[WS_HB + (size_t)(b*16+(u>>8))*256 + (u&255)];
            __syncthreads();
            if(tid<192){
                int p = tid>>6, d = tid&63;           // p: 0=q 1=k 2=v
                int row = l*768 + p*256 + hh*64 + d;
                const float* wr = qkvW + (size_t)row*256;
                float bias = qkvb[row];
                float acc[16];
#pragma unroll
                for(int s=0;s<16;++s) acc[s]=bias;
                for(int k=0;k<256;k+=4){
                    float4 w4 = *(const float4*)(wr+k);
#pragma unroll
                    for(int s=0;s<16;++s){
                        float4 h4 = *(const float4*)&s_h[s][k];
                        acc[s] += w4.x*h4.x + w4.y*h4.y + w4.z*h4.z + w4.w*h4.w;
                    }
                }
#pragma unroll
                for(int s=0;s<16;++s) s_qkv[p][s][d] = acc[s];
            }
            __syncthreads();
            if(tid<256){
                int s = tid>>4, t = tid&15;
                float a=0.f;
#pragma unroll
                for(int d=0; d<64; ++d) a += s_qkv[0][s][d]*s_qkv[1][t][d];
                s_sc[s][t] = a*0.125f;
            }
            __syncthreads();
            if(tid<16){
                int r=tid;
                float m=-1e30f;
#pragma unroll
                for(int tt=0;tt<16;++tt) m=fmaxf(m,s_sc[r][tt]);
                float e[16]; float sum=0.f;
#pragma unroll
                for(int tt=0;tt<16;++tt){ e[tt]=__expf(s_sc[r][tt]-m); sum+=e[tt]; }
                float inv=1.0f/sum;
#pragma unroll
                for(int tt=0;tt<16;++tt) s_sc[r][tt]=e[tt]*inv;
            }
            __syncthreads();
            for(int u=tid; u<1024; u+=512){
                int s=u>>6, d=u&63;
                float o=0.f;
#pragma unroll
                for(int t2=0;t2<16;++t2) o += s_sc[s][t2]*s_qkv[2][t2][d];
                ws[WS_AO + (size_t)(b*16+s)*256 + hh*64 + d] = o;
            }
        } else if(l==0){
            // ============ P: prepm, 16 rows per block ============
            int pb = bx - 64;                         // 0..63
            float* wrow = &s_f1[0][0];                // [2][256]
            float* redf = &s_red[0][0];               // 32 slots
            signed char* q8 = (signed char*)&s_sc[0][0]; // 512 B
            int rh = tid>>8, c = tid&255, wv = tid>>6;
            for(int it=0; it<8; ++it){
                int r = pb*16 + it*2 + rh;
                bool hasA = (r < 768);
                wrow[rh*256+c] = hasA ? Wih[(size_t)r*256+c] : 0.0f;
                __syncthreads();
                float m;
                if(hasA){
                    float a = 0.f;
                    for(int k=0;k<256;++k) a += wrow[rh*256+k]*outW[(size_t)k*256+c];
                    if(r<512) a += Whh[(size_t)r*256+c];
                    m = a;
                } else {
                    m = Whh[(size_t)(r-256)*256+c];
                }
                float pv = wrow[rh*256+c]*outb[c];
                for(int mk=1; mk<64; mk<<=1) pv += __shfl_xor(pv, mk);
                if((tid&63)==0) redf[wv] = pv;
                __syncthreads();
                if(c==0){
                    float cs = redf[rh*4+0]+redf[rh*4+1]+redf[rh*4+2]+redf[rh*4+3];
                    float cv;
                    if(r<512)       cv = cs + bih[r] + bhh[r];
                    else if(r<768)  cv = cs + bih[r];
                    else            cv = bhh[r-256];
                    ws[WS_CV + r] = cv;
                }
                float av = fabsf(m);
                for(int mk=1; mk<64; mk<<=1) av = fmaxf(av, __shfl_xor(av, mk));
                if((tid&63)==0) redf[16+wv] = av;
                __syncthreads();
                float rowmax = fmaxf(fmaxf(redf[16+rh*4],redf[17+rh*4]),
                                     fmaxf(redf[18+rh*4],redf[19+rh*4]));
                float inv = rowmax>0.f ? 127.0f/rowmax : 0.0f;
                q8[rh*256+c] = (signed char)__float2int_rn(m*inv);
                if(c==0) ws[WS_MS + r] = rowmax>0.f ? rowmax*(1.0f/(127.0f*127.0f)) : 0.0f;
                __syncthreads();
                if(c<64){
                    uint_t u = ((uint_t)(unsigned char)q8[rh*256+4*c  ])
                             | ((uint_t)(unsigned char)q8[rh*256+4*c+1] << 8)
                             | ((uint_t)(unsigned char)q8[rh*256+4*c+2] << 16)
                             | ((uint_t)(unsigned char)q8[rh*256+4*c+3] << 24);
                    ((uint_t*)ws)[WS_M8 + (size_t)r*64 + c] = u;
                }
                __syncthreads();
            }
        }
        grid.sync();                                        // 2 / 4

        // ============ F: ao + LN1 + ffn1 + ffn2 + LN2 (2 tokens) ============
        {
            int tk = tid>>8, i = tid&255;
            int bs = bx*2 + tk;
            s_h[tk][i] = ws[WS_AO + (size_t)bs*256 + i];
            float hb = ws[WS_HB + (size_t)bs*256 + i];
            __syncthreads();
            const float* wr = aoW + (size_t)(l*256+i)*256;
            float acc = aob[l*256+i];
            for(int k=0;k<256;k+=4){
                float4 w4 = *(const float4*)(wr+k);
                float4 h4 = *(const float4*)&s_h[tk][k];
                acc += w4.x*h4.x + w4.y*h4.y + w4.z*h4.z + w4.w*h4.w;
            }
            float x = hb + acc;
            // LN1
            s_red[tk][i]=x; __syncthreads();
            for(int off=128;off>0;off>>=1){ if(i<off) s_red[tk][i]+=s_red[tk][i+off]; __syncthreads(); }
            float mn = s_red[tk][0]*(1.0f/256.0f); __syncthreads();
            float d = x-mn;
            s_red[tk][i]=d*d; __syncthreads();
            for(int off=128;off>0;off>>=1){ if(i<off) s_red[tk][i]+=s_red[tk][i+off]; __syncthreads(); }
            float vv = s_red[tk][0]*(1.0f/256.0f);
            float h1 = (d / sqrtf(vv+1e-5f))*g1[l*256+i] + b1[l*256+i];
            __syncthreads();
            s_h[2+tk][i] = h1;
            __syncthreads();
            // ffn1
#pragma unroll
            for(int jj=0;jj<4;++jj){
                int j = jj*256 + i;
                const float* w1r = W1 + (size_t)(l*1024+j)*256;
                float a1 = fb1[l*1024+j];
                for(int k=0;k<256;k+=4){
                    float4 w4 = *(const float4*)(w1r+k);
                    float4 h4 = *(const float4*)&s_h[2+tk][k];
                    a1 += w4.x*h4.x + w4.y*h4.y + w4.z*h4.z + w4.w*h4.w;
                }
                s_f1[tk][j] = fmaxf(a1, 0.0f);
            }
            __syncthreads();
            // ffn2
            const float* w2r = W2 + (size_t)(l*256+i)*1024;
            float a2 = fb2[l*256+i];
            for(int k=0;k<1024;k+=4){
                float4 w4 = *(const float4*)(w2r+k);
                float4 h4 = *(const float4*)&s_f1[tk][k];
                a2 += w4.x*h4.x + w4.y*h4.y + w4.z*h4.z + w4.w*h4.w;
            }
            float x2 = h1 + a2;
            // LN2
            s_red[tk][i]=x2; __syncthreads();
            for(int off=128;off>0;off>>=1){ if(i<off) s_red[tk][i]+=s_red[tk][i+off]; __syncthreads(); }
            float mn2 = s_red[tk][0]*(1.0f/256.0f); __syncthreads();
            float d2 = x2-mn2;
            s_red[tk][i]=d2*d2; __syncthreads();
            for(int off=128;off>0;off>>=1){ if(i<off) s_red[tk][i]+=s_red[tk][i+off]; __syncthreads(); }
            float vv2 = s_red[tk][0]*(1.0f/256.0f);
            float y2 = d2 / sqrtf(vv2+1e-5f);
            ws[WS_HB + (size_t)bs*256 + i] = y2*g2[l*256+i] + b2v[l*256+i];
        }
        grid.sync();                                        // 3 / 5
    }

    // ================= LG: latent mean + gi0 (blocks 0-15) =================
    if(bx < 16){
        float* lat = &s_sc[0][0];
        if(tid<256){
            float a=0.f;
#pragma unroll
            for(int s=0;s<16;++s) a += ws[WS_HB + (size_t)(bx*16+s)*256 + tid];
            lat[tid] = a*(1.0f/16.0f);
        }
        __syncthreads();
        for(int j=tid; j<768; j+=512){
            const float* wr = Wih + (size_t)j*256;
            float acc = bih[j];
            for(int k=0;k<256;k+=4){
                float4 w4=*(const float4*)(wr+k);
                float4 l4=*(const float4*)&lat[k];
                acc += w4.x*l4.x + w4.y*l4.y + w4.z*l4.z + w4.w*l4.w;
            }
            ws[WS_GI0 + (size_t)bx*768 + j] = acc;
        }
    }
    grid.sync();                                            // 6

    // ================= CH: sequential GRU chain (blocks 0-15) ==============
    if(bx < 16){
        int b   = bx;
        int ln  = tid & 63;
        int w   = tid >> 6;
        int col = ln & 15;
        int grp = ln >> 4;
        int par = grp & 1;
        int ge  = w*32 + par*16 + col;

        const uint_t* Mdw = (const uint_t*)ws + WS_M8;
        v4i wf[8][4];
#pragma unroll
        for(int s=0;s<4;++s){
#pragma unroll
            for(int half=0; half<2; ++half){
                int f = s*2 + half;
                int row = s*256 + w*32 + half*16 + col;
                const uint_t* src = Mdw + (size_t)row*64 + grp*4;
#pragma unroll
                for(int kt=0;kt<4;++kt)
                    wf[f][kt] = *(const v4i*)(src + kt*16);
            }
        }
        float Cs[4], MSs[4];
#pragma unroll
        for(int s=0;s<4;++s){
            int row = s*256 + ge;
            Cs[s]  = ws[WS_CV + row];
            MSs[s] = ws[WS_MS + row];
        }

        const float* gi = ws + WS_GI0 + (size_t)b*768;
        float r0 = sigf(gi[ge]     + bhh[ge]);
        float z0 = sigf(gi[256+ge] + bhh[256+ge]);
        float n0 = tanh_fast(gi[512+ge] + r0*bhh[512+ge]);
        float hp = (1.0f-z0)*n0;

        float* hsp = ws + WS_HSEQ + (size_t)b*256;
        if(grp < 2){
            s_h8[0][w*32 + (ln&31)] = (signed char)__float2int_rn(hp*127.0f);
            hsp[w*32 + (ln&31)] = hp;
        }
        asm volatile("s_waitcnt lgkmcnt(0)" ::: "memory");
        __builtin_amdgcn_s_barrier();
        asm volatile("" ::: "memory");

        const v4i vzero = {0,0,0,0};
        int po = 0;
        for(int t=1; t<1028; ++t){
            hsp += 4096;
            v4i af[4];
#pragma unroll
            for(int kt=0;kt<4;++kt)
                af[kt] = *(const v4i*)&s_h8[po][kt*64 + grp*16];
            v4i acc[8];
#pragma unroll
            for(int f=0;f<8;++f){
                acc[f] = __builtin_amdgcn_mfma_i32_16x16x64_i8(af[0], wf[f][0], vzero, 0,0,0);
#pragma unroll
                for(int kt=1;kt<4;++kt)
                    acc[f] = __builtin_amdgcn_mfma_i32_16x16x64_i8(af[kt], wf[f][kt], acc[f], 0,0,0);
            }
            int a_r = par ? acc[1][0] : acc[0][0];
            int a_z = par ? acc[3][0] : acc[2][0];
            int a_n = par ? acc[5][0] : acc[4][0];
            int a_h = par ? acc[7][0] : acc[6][0];
            float yr = MSs[0]*(float)a_r + Cs[0];
            float yz = MSs[1]*(float)a_z + Cs[1];
            float yn = MSs[2]*(float)a_n + Cs[2];
            float yh = MSs[3]*(float)a_h + Cs[3];
            float rr = sigf(yr);
            float zz = sigf(yz);
            float nn = tanh_fast(yn + rr*yh);
            hp = (1.0f-zz)*nn + zz*hp;
            if(grp < 2){
                s_h8[po^1][w*32 + (ln&31)] = (signed char)__float2int_rn(hp*127.0f);
                hsp[w*32 + (ln&31)] = hp;
            }
            asm volatile("s_waitcnt lgkmcnt(0)" ::: "memory");
            __builtin_amdgcn_s_barrier();
            asm volatile("" ::: "memory");
            po ^= 1;
        }
    }
    grid.sync();                                            // 7

    // ================= EPI: output GEMM (8-9 chunks/block) =================
    for(int t=bx; t<1028; t+=128){
        for(int u=tid; u<4096; u+=512)
            (&s_h[0][0])[u] = ws[WS_HSEQ + (size_t)t*4096 + u];
        __syncthreads();
        int j = tid & 255, half = tid >> 8;
        const float* wr = outW + (size_t)j*256;
        float bias = outb[j];
        float acc[8];
#pragma unroll
        for(int bb=0;bb<8;++bb) acc[bb]=bias;
        for(int k=0;k<256;k+=4){
            float4 w4 = *(const float4*)(wr+k);
#pragma unroll
            for(int bb=0;bb<8;++bb){
                float4 h4 = *(const float4*)&s_h[half*8+bb][k];
                acc[bb] += w4.x*h4.x + w4.y*h4.y + w4.z*h4.z + w4.w*h4.w;
            }
        }
#pragma unroll
        for(int bb=0;bb<8;++bb)
            out[(size_t)(half*8+bb)*263168 + (size_t)t*256 + j] = acc[bb];
        __syncthreads();
    }
}

// ======================= launch ============================================

extern "C" void kernel_launch(void* const* d_in, const int* in_sizes, int n_in,
                              void* d_out, int out_size, void* d_ws, size_t ws_size,
                              hipStream_t stream){
    const float* gs   = (const float*)d_in[0];
    const float* eW   = (const float*)d_in[1];
    const float* eb   = (const float*)d_in[2];
    const float* qkvW = (const float*)d_in[3];
    const float* qkvb = (const float*)d_in[4];
    const float* aoW  = (const float*)d_in[5];
    const float* aob  = (const float*)d_in[6];
    const float* g1   = (const float*)d_in[7];
    const float* b1   = (const float*)d_in[8];
    const float* g2   = (const float*)d_in[9];
    const float* b2   = (const float*)d_in[10];
    const float* W1   = (const float*)d_in[11];
    const float* fb1  = (const float*)d_in[12];
    const float* W2   = (const float*)d_in[13];
    const float* fb2  = (const float*)d_in[14];
    const float* Wih  = (const float*)d_in[15];
    const float* Whh  = (const float*)d_in[16];
    const float* bih  = (const float*)d_in[17];
    const float* bhh  = (const float*)d_in[18];
    const float* outW = (const float*)d_in[19];
    const float* outb = (const float*)d_in[20];
    float* ws  = (float*)d_ws;
    float* out = (float*)d_out;

    void* args[] = {
        (void*)&gs, (void*)&eW, (void*)&eb, (void*)&qkvW, (void*)&qkvb,
        (void*)&aoW, (void*)&aob, (void*)&g1, (void*)&b1, (void*)&g2,
        (void*)&b2, (void*)&W1, (void*)&fb1, (void*)&W2, (void*)&fb2,
        (void*)&Wih, (void*)&bih, (void*)&Whh, (void*)&bhh, (void*)&outW,
        (void*)&outb, (void*)&ws, (void*)&out
    };
    hipLaunchCooperativeKernel((const void*)k_all, dim3(128), dim3(512),
                               args, 0, stream);
}